// Round 4
// baseline (238.502 us; speedup 1.0000x reference)
//
#include <hip/hip_runtime.h>
#include <hip/hip_bf16.h>
#include <math.h>

typedef __attribute__((ext_vector_type(8))) short bf16x8;   // 8 bf16 = 4 VGPR
typedef __attribute__((ext_vector_type(4))) float f32x4;
typedef __attribute__((ext_vector_type(16))) float f32x16;
typedef __attribute__((ext_vector_type(4))) unsigned int u32x4;

static constexpr int Mtot = 8192;   // B*S
static constexpr int Dmod = 1024;
static constexpr int SEQ  = 2048;
static constexpr int NH   = 16;
static constexpr int DH   = 64;

// softmax scale folded into Q projection, in exp2 domain: (1/8) * log2(e)
static constexpr float QSCALE = 0.18033688011112042f;

// fp32 -> bf16 RNE
__device__ __forceinline__ unsigned short f2bf(float x) {
    unsigned int u = __float_as_uint(x);
    u += 0x7fff + ((u >> 16) & 1);
    return (unsigned short)(u >> 16);
}

// async global->LDS, 16B per lane. LDS dest = wave-uniform base + lane*16.
__device__ __forceinline__ void gload_lds16(const void* g, void* l) {
    __builtin_amdgcn_global_load_lds(
        (const __attribute__((address_space(1))) unsigned int*)g,
        (__attribute__((address_space(3))) unsigned int*)l, 16, 0, 0);
}

// ---------------------------------------------------------------------------
// x fp32 -> bf16
// ---------------------------------------------------------------------------
__global__ __launch_bounds__(256)
void cvt_bf16(const float* __restrict__ in, unsigned short* __restrict__ out, int n4) {
    int i = blockIdx.x * blockDim.x + threadIdx.x;
    const int stride = gridDim.x * blockDim.x;
    for (; i < n4; i += stride) {
        float4 v = ((const float4*)in)[i];
        ushort4 o;
        o.x = f2bf(v.x); o.y = f2bf(v.y); o.z = f2bf(v.z); o.w = f2bf(v.w);
        ((ushort4*)out)[i] = o;
    }
}

// ---------------------------------------------------------------------------
// W[k][n] fp32 -> Wt[n][k] bf16
// ---------------------------------------------------------------------------
__global__ __launch_bounds__(256)
void transpose_cvt(const float* __restrict__ W, unsigned short* __restrict__ Wt) {
    __shared__ float tile[64][68];
    const int n0 = blockIdx.x * 64, k0 = blockIdx.y * 64;
    const int t = threadIdx.x;
    const int r = t >> 4, c4 = (t & 15) * 4;
#pragma unroll
    for (int i = 0; i < 4; ++i) {
        float4 v = *(const float4*)&W[(size_t)(k0 + r + i * 16) * Dmod + n0 + c4];
        tile[c4 + 0][r + i * 16] = v.x;
        tile[c4 + 1][r + i * 16] = v.y;
        tile[c4 + 2][r + i * 16] = v.z;
        tile[c4 + 3][r + i * 16] = v.w;
    }
    __syncthreads();
#pragma unroll
    for (int i = 0; i < 4; ++i) {
        ushort4 o;
        o.x = f2bf(tile[r + i * 16][c4 + 0]);
        o.y = f2bf(tile[r + i * 16][c4 + 1]);
        o.z = f2bf(tile[r + i * 16][c4 + 2]);
        o.w = f2bf(tile[r + i * 16][c4 + 3]);
        *(ushort4*)&Wt[(size_t)(n0 + r + i * 16) * Dmod + k0 + c4] = o;
    }
}

// ---------------------------------------------------------------------------
// MFMA GEMM core: 128x128 tile, BK=32, 4 waves (2x2), 64x64 per wave.
// ---------------------------------------------------------------------------
__device__ __forceinline__ void gemm_core(const unsigned short* __restrict__ A,
                                          const unsigned short* __restrict__ Wt,
                                          int m0, int n0, int K,
                                          short* As, short* Bs, f32x4 acc[4][4]) {
    const int t   = threadIdx.x;
    const int wid = t >> 6, l = t & 63;
    const int wr  = wid >> 1, wc = wid & 1;
    const int r16 = l & 15, g = l >> 4;
    const int srow = t >> 2;
    const int scol = (t & 3) * 8;

    for (int k0 = 0; k0 < K; k0 += 32) {
        __syncthreads();
#pragma unroll
        for (int c = 0; c < 2; ++c) {
            gload_lds16(A  + (size_t)(m0 + c * 64 + srow) * K + k0 + scol,
                        (char*)As + c * 4096 + wid * 1024);
            gload_lds16(Wt + (size_t)(n0 + c * 64 + srow) * K + k0 + scol,
                        (char*)Bs + c * 4096 + wid * 1024);
        }
        __syncthreads();
        bf16x8 af[4], bv[4];
#pragma unroll
        for (int mi = 0; mi < 4; ++mi)
            af[mi] = *(const bf16x8*)&As[(wr * 64 + mi * 16 + r16) * 32 + g * 8];
#pragma unroll
        for (int ni = 0; ni < 4; ++ni)
            bv[ni] = *(const bf16x8*)&Bs[(wc * 64 + ni * 16 + r16) * 32 + g * 8];
#pragma unroll
        for (int mi = 0; mi < 4; ++mi)
#pragma unroll
            for (int ni = 0; ni < 4; ++ni)
                acc[mi][ni] = __builtin_amdgcn_mfma_f32_16x16x32_bf16(
                    af[mi], bv[ni], acc[mi][ni], 0, 0, 0);
    }
}

// ---------------------------------------------------------------------------
// Fused QKV projection. Q gets QSCALE folded in (exp2-domain softmax).
// ---------------------------------------------------------------------------
__global__ __launch_bounds__(256)
void qkv_gemm(const unsigned short* __restrict__ xb,
              const unsigned short* __restrict__ wtq,
              const unsigned short* __restrict__ wtk,
              const unsigned short* __restrict__ wtv,
              unsigned short* __restrict__ Qb,
              unsigned short* __restrict__ Kb,
              unsigned short* __restrict__ Vtb) {
    __shared__ __align__(16) short As[128 * 32];
    __shared__ __align__(16) short Bs[128 * 32];
    const int region = blockIdx.x >> 3;
    const int n0 = (blockIdx.x & 7) * 128;
    const int m0 = blockIdx.y * 128;
    const unsigned short* Wt = region == 0 ? wtq : (region == 1 ? wtk : wtv);

    f32x4 acc[4][4];
    const f32x4 z = {0.f, 0.f, 0.f, 0.f};
#pragma unroll
    for (int i = 0; i < 4; ++i)
#pragma unroll
        for (int j = 0; j < 4; ++j) acc[i][j] = z;

    gemm_core(xb, Wt, m0, n0, Dmod, As, Bs, acc);

    const int t = threadIdx.x, wid = t >> 6, l = t & 63;
    const int wr = wid >> 1, wc = wid & 1, r16 = l & 15, g = l >> 4;

    if (region <= 1) {
        unsigned short* out = region ? Kb : Qb;
        const float qs = region == 0 ? QSCALE : 1.0f;
#pragma unroll
        for (int mi = 0; mi < 4; ++mi) {
            const int mrow = m0 + wr * 64 + mi * 16 + g * 4;
#pragma unroll
            for (int ni = 0; ni < 4; ++ni) {
                const int ncol = n0 + wc * 64 + ni * 16 + r16;
#pragma unroll
                for (int reg = 0; reg < 4; ++reg)
                    out[(size_t)(mrow + reg) * Dmod + ncol] = f2bf(acc[mi][ni][reg] * qs);
            }
        }
    } else {
#pragma unroll
        for (int mi = 0; mi < 4; ++mi) {
            const int mrow = m0 + wr * 64 + mi * 16 + g * 4;
            const int b = mrow >> 11, s = mrow & 2047;
#pragma unroll
            for (int ni = 0; ni < 4; ++ni) {
                const int n = n0 + wc * 64 + ni * 16 + r16;
                const int bh = b * NH + (n >> 6), d = n & 63;
                ushort4 o;
                o.x = f2bf(acc[mi][ni][0]); o.y = f2bf(acc[mi][ni][1]);
                o.z = f2bf(acc[mi][ni][2]); o.w = f2bf(acc[mi][ni][3]);
                *(ushort4*)&Vtb[((size_t)bh * DH + d) * SEQ + s] = o;
            }
        }
    }
}

// ---------------------------------------------------------------------------
// Output projection
// ---------------------------------------------------------------------------
__global__ __launch_bounds__(256)
void out_gemm(const unsigned short* __restrict__ Cx,
              const unsigned short* __restrict__ wto,
              const float* __restrict__ bias,
              float* __restrict__ out) {
    __shared__ __align__(16) short As[128 * 32];
    __shared__ __align__(16) short Bs[128 * 32];
    const int n0 = blockIdx.x * 128, m0 = blockIdx.y * 128;

    f32x4 acc[4][4];
    const f32x4 z = {0.f, 0.f, 0.f, 0.f};
#pragma unroll
    for (int i = 0; i < 4; ++i)
#pragma unroll
        for (int j = 0; j < 4; ++j) acc[i][j] = z;

    gemm_core(Cx, wto, m0, n0, Dmod, As, Bs, acc);

    const int t = threadIdx.x, wid = t >> 6, l = t & 63;
    const int wr = wid >> 1, wc = wid & 1, r16 = l & 15, g = l >> 4;
    float bv[4];
#pragma unroll
    for (int ni = 0; ni < 4; ++ni) bv[ni] = bias[n0 + wc * 64 + ni * 16 + r16];
#pragma unroll
    for (int mi = 0; mi < 4; ++mi) {
        const int mrow = m0 + wr * 64 + mi * 16 + g * 4;
#pragma unroll
        for (int ni = 0; ni < 4; ++ni) {
            const int ncol = n0 + wc * 64 + ni * 16 + r16;
#pragma unroll
            for (int reg = 0; reg < 4; ++reg)
                out[(size_t)(mrow + reg) * Dmod + ncol] = acc[mi][ni][reg] + bv[ni];
        }
    }
}

// ---------------------------------------------------------------------------
// MFMA flash attention, v3: 32x32x16 MFMA, in-register P, defer-max.
//  * 512 blocks, pair-balanced (34 kv-tiles each), XCD-local bh decode.
//  * Swapped QK^T: S^T = mfma(K, Q), col = q = lane&31; row-reduce = 15 fmax
//    + 1 shfl_xor(32). P stays in registers: cvt_pk_bf16 + permlane32_swap
//    build PV A-fragments directly (no P LDS round-trip).
//  * Defer-max (THR=8, exp2 domain): O-rescale is a rare wave-uniform branch.
//  * LDS = K/V double-buffer only (33 KB); Q fragments read from global.
// ---------------------------------------------------------------------------
__global__ __launch_bounds__(256, 4)
void attn_mfma(const unsigned short* __restrict__ Qg,
               const unsigned short* __restrict__ Kg,
               const unsigned short* __restrict__ Vtg,
               unsigned short* __restrict__ Ctx) {
    __shared__ __align__(16) short Ks[2][64 * 64];   // 16 KB
    __shared__ __align__(16) short Vs[2][64 * 64];   // 16 KB (Vt: [d][kv])
    __shared__ float sm[4][32];                      // per-wave scale/l bcast

    const int id   = blockIdx.x;                  // 0..511
    const int bh   = ((id >> 6) << 3) | (id & 7); // id%8 = XCD = bh low bits
    const int pidx = (id >> 3) & 7;
    const int b = bh >> 4, h = bh & 15;
    const int t = threadIdx.x, wid = t >> 6, l = t & 63;
    const int lo = l & 31, hi = l >> 5;
    const int srow8 = t >> 3, scolb = (t & 7) * 16;

    auto stageKV = [&](int jt, int buf) {
        const int k0s = jt * 64;
#pragma unroll
        for (int c = 0; c < 2; ++c) {
            const int row = c * 32 + srow8;
            const int swz = scolb ^ ((row & 7) << 4);
            gload_lds16((const char*)Kg + ((size_t)(b * SEQ + k0s + row) * Dmod + h * DH) * 2 + swz,
                        (char*)&Ks[buf][0] + c * 4096 + wid * 1024);
            gload_lds16((const char*)Vtg + ((size_t)(bh * DH + row) * SEQ + k0s) * 2 + swz,
                        (char*)&Vs[buf][0] + c * 4096 + wid * 1024);
        }
    };

    int cur = 0;
    for (int pass = 0; pass < 2; ++pass) {
        const int qt = pass ? pidx : 15 - pidx;   // heavy tile first
        const int q0 = qt * 128;
        const int qw0 = q0 + wid * 32;
        const int qg = qw0 + lo;                  // this lane's q row (S^T col)

        // Q fragments straight from global (B-operand: col=q=lane&31, k=d)
        bf16x8 bq[4];
#pragma unroll
        for (int dc = 0; dc < 4; ++dc)
            bq[dc] = *(const bf16x8*)&Qg[(size_t)(b * SEQ + qg) * Dmod + h * DH + dc * 16 + 8 * hi];

        stageKV(0, cur);

        float m_run = -1e30f, l_run = 0.f;
        f32x16 oacc[2];
#pragma unroll
        for (int nb = 0; nb < 2; ++nb)
#pragma unroll
            for (int r = 0; r < 16; ++r) oacc[nb][r] = 0.f;

        __syncthreads();                          // KV0 landed (+ buffers free)

        const int jmax = 2 * qt + 1;
        for (int jt = 0; jt <= jmax; ++jt) {
            if (jt < jmax) stageKV(jt + 1, cur ^ 1);   // prefetch next tile
            const char* Kc = (const char*)&Ks[cur][0];
            const char* Vc = (const char*)&Vs[cur][0];
            const bool diag = (jt >= 2 * qt);

#pragma unroll
            for (int c32 = 0; c32 < 2; ++c32) {
                // ---- S^T chunk = mfma(K, Q): rows kv (32), cols q (32)
                const int krow = c32 * 32 + lo;
                const int kswz = (krow & 7) << 4;
                bf16x8 ak[4];
#pragma unroll
                for (int dc = 0; dc < 4; ++dc)
                    ak[dc] = *(const bf16x8*)(Kc + krow * 128 + ((dc * 32 + 16 * hi) ^ kswz));
                f32x16 st;
#pragma unroll
                for (int r = 0; r < 16; ++r) st[r] = 0.f;
                __builtin_amdgcn_s_setprio(1);
#pragma unroll
                for (int dc = 0; dc < 4; ++dc)
                    st = __builtin_amdgcn_mfma_f32_32x32x16_bf16(ak[dc], bq[dc], st, 0, 0, 0);
                __builtin_amdgcn_s_setprio(0);

                if (diag) {
                    const int kvb = jt * 64 + c32 * 32 + 4 * hi;
#pragma unroll
                    for (int r = 0; r < 16; ++r) {
                        const int kvg = kvb + (r & 3) + 8 * (r >> 2);
                        if (kvg > qg) st[r] = -1e30f;
                    }
                }

                // ---- online softmax, defer-max (exp2 domain)
                float pmax = st[0];
#pragma unroll
                for (int r = 1; r < 16; ++r) pmax = fmaxf(pmax, st[r]);
                pmax = fmaxf(pmax, __shfl_xor(pmax, 32));

                if (!__all(pmax <= m_run + 8.f)) {       // rare rescale path
                    const float mnew = fmaxf(m_run, pmax);
                    const float sc = exp2f(m_run - mnew);
                    l_run *= sc;
                    m_run = mnew;
                    if (l < 32) sm[wid][lo] = sc;
                    asm volatile("s_waitcnt lgkmcnt(0)" ::: "memory");
#pragma unroll
                    for (int rq = 0; rq < 4; ++rq) {
                        const f32x4 s4 = *(const f32x4*)&sm[wid][8 * rq + 4 * hi];
#pragma unroll
                        for (int e = 0; e < 4; ++e) {
                            oacc[0][rq * 4 + e] *= s4[e];
                            oacc[1][rq * 4 + e] *= s4[e];
                        }
                    }
                }

                float p[16];
                float rsum = 0.f;
#pragma unroll
                for (int r = 0; r < 16; ++r) { p[r] = exp2f(st[r] - m_run); rsum += p[r]; }
                rsum += __shfl_xor(rsum, 32);
                l_run += rsum;

                // ---- in-register P -> A-fragments, PV accumulate
#pragma unroll
                for (int kb = 0; kb < 2; ++kb) {
                    unsigned int x, zz, y, w;
                    asm("v_cvt_pk_bf16_f32 %0, %1, %2" : "=v"(x)  : "v"(p[kb*8+0]), "v"(p[kb*8+1]));
                    asm("v_cvt_pk_bf16_f32 %0, %1, %2" : "=v"(zz) : "v"(p[kb*8+2]), "v"(p[kb*8+3]));
                    asm("v_cvt_pk_bf16_f32 %0, %1, %2" : "=v"(y)  : "v"(p[kb*8+4]), "v"(p[kb*8+5]));
                    asm("v_cvt_pk_bf16_f32 %0, %1, %2" : "=v"(w)  : "v"(p[kb*8+6]), "v"(p[kb*8+7]));
                    asm volatile("v_permlane32_swap_b32 %0, %1" : "+v"(x),  "+v"(y));
                    asm volatile("v_permlane32_swap_b32 %0, %1" : "+v"(zz), "+v"(w));
                    u32x4 aw; aw[0] = x; aw[1] = zz; aw[2] = y; aw[3] = w;
                    const bf16x8 paf = __builtin_bit_cast(bf16x8, aw);

                    const int vbyte = c32 * 64 + kb * 32 + 16 * hi;
                    const int row0 = lo, row1 = 32 + lo;
                    const bf16x8 vb0 = *(const bf16x8*)(Vc + row0 * 128 + (vbyte ^ ((row0 & 7) << 4)));
                    const bf16x8 vb1 = *(const bf16x8*)(Vc + row1 * 128 + (vbyte ^ ((row1 & 7) << 4)));

                    __builtin_amdgcn_s_setprio(1);
                    oacc[0] = __builtin_amdgcn_mfma_f32_32x32x16_bf16(paf, vb0, oacc[0], 0, 0, 0);
                    oacc[1] = __builtin_amdgcn_mfma_f32_32x32x16_bf16(paf, vb1, oacc[1], 0, 0, 0);
                    __builtin_amdgcn_s_setprio(0);
                }
            }
            __syncthreads();    // prefetch landed (vmcnt drain); reads done
            cur ^= 1;
        }

        // ---- epilogue: broadcast l to O-row domain, write ctx bf16
        if (l < 32) sm[wid][lo] = l_run;
        asm volatile("s_waitcnt lgkmcnt(0)" ::: "memory");
#pragma unroll
        for (int rq = 0; rq < 4; ++rq) {
            const f32x4 lv = *(const f32x4*)&sm[wid][8 * rq + 4 * hi];
#pragma unroll
            for (int e = 0; e < 4; ++e) {
                const float inv = 1.0f / lv[e];
                const int qrow = qw0 + 8 * rq + 4 * hi + e;
                const size_t rb = (size_t)(b * SEQ + qrow) * Dmod + h * DH + lo;
                Ctx[rb]      = f2bf(oacc[0][rq * 4 + e] * inv);
                Ctx[rb + 32] = f2bf(oacc[1][rq * 4 + e] * inv);
            }
        }
    }
}

// ---------------------------------------------------------------------------
extern "C" void kernel_launch(void* const* d_in, const int* in_sizes, int n_in,
                              void* d_out, int out_size, void* d_ws, size_t ws_size,
                              hipStream_t stream) {
    const float* x  = (const float*)d_in[0];
    const float* Wq = (const float*)d_in[1];
    const float* Wk = (const float*)d_in[2];
    const float* Wv = (const float*)d_in[3];
    const float* Wo = (const float*)d_in[4];
    const float* bo = (const float*)d_in[5];
    float* out = (float*)d_out;

    const size_t MD = (size_t)Mtot * Dmod;
    const size_t DD = (size_t)Dmod * Dmod;
    unsigned short* xb  = (unsigned short*)d_ws;
    unsigned short* wtq = xb  + MD;
    unsigned short* wtk = wtq + DD;
    unsigned short* wtv = wtk + DD;
    unsigned short* wto = wtv + DD;
    unsigned short* Qb  = wto + DD;
    unsigned short* Kb  = Qb  + MD;
    unsigned short* Vtb = Kb  + MD;
    unsigned short* Cx  = Vtb + MD;

    cvt_bf16<<<2048, 256, 0, stream>>>(x, xb, (int)(MD / 4));
    transpose_cvt<<<dim3(16, 16), 256, 0, stream>>>(Wq, wtq);
    transpose_cvt<<<dim3(16, 16), 256, 0, stream>>>(Wk, wtk);
    transpose_cvt<<<dim3(16, 16), 256, 0, stream>>>(Wv, wtv);
    transpose_cvt<<<dim3(16, 16), 256, 0, stream>>>(Wo, wto);

    qkv_gemm<<<dim3(24, 64), 256, 0, stream>>>(xb, wtq, wtk, wtv, Qb, Kb, Vtb);

    attn_mfma<<<512, 256, 0, stream>>>(Qb, Kb, Vtb, Cx);

    out_gemm<<<dim3(8, 64), 256, 0, stream>>>(Cx, wto, bo, out);
}

// Round 5
// 204.060 us; speedup vs baseline: 1.1688x; 1.1688x over previous
//
#include <hip/hip_runtime.h>
#include <hip/hip_bf16.h>
#include <math.h>

typedef __attribute__((ext_vector_type(8))) short bf16x8;   // 8 bf16 = 4 VGPR
typedef __attribute__((ext_vector_type(4))) float f32x4;
typedef __attribute__((ext_vector_type(16))) float f32x16;
typedef __attribute__((ext_vector_type(4))) unsigned int u32x4;

static constexpr int Mtot = 8192;   // B*S
static constexpr int Dmod = 1024;
static constexpr int SEQ  = 2048;
static constexpr int NH   = 16;
static constexpr int DH   = 64;

// softmax scale folded into Q projection, in exp2 domain: (1/8) * log2(e)
static constexpr float QSCALE = 0.18033688011112042f;

// fp32 -> bf16 RNE
__device__ __forceinline__ unsigned short f2bf(float x) {
    unsigned int u = __float_as_uint(x);
    u += 0x7fff + ((u >> 16) & 1);
    return (unsigned short)(u >> 16);
}

// async global->LDS, 16B per lane. LDS dest = wave-uniform base + lane*16.
__device__ __forceinline__ void gload_lds16(const void* g, void* l) {
    __builtin_amdgcn_global_load_lds(
        (const __attribute__((address_space(1))) unsigned int*)g,
        (__attribute__((address_space(3))) unsigned int*)l, 16, 0, 0);
}

// ---------------------------------------------------------------------------
// x fp32 -> bf16
// ---------------------------------------------------------------------------
__global__ __launch_bounds__(256)
void cvt_bf16(const float* __restrict__ in, unsigned short* __restrict__ out, int n4) {
    int i = blockIdx.x * blockDim.x + threadIdx.x;
    const int stride = gridDim.x * blockDim.x;
    for (; i < n4; i += stride) {
        float4 v = ((const float4*)in)[i];
        ushort4 o;
        o.x = f2bf(v.x); o.y = f2bf(v.y); o.z = f2bf(v.z); o.w = f2bf(v.w);
        ((ushort4*)out)[i] = o;
    }
}

// ---------------------------------------------------------------------------
// All four W[k][n] fp32 -> Wt[n][k] bf16 in one launch (z = which weight)
// ---------------------------------------------------------------------------
__global__ __launch_bounds__(256)
void transpose_cvt4(const float* __restrict__ W0, const float* __restrict__ W1,
                    const float* __restrict__ W2, const float* __restrict__ W3,
                    unsigned short* __restrict__ T0, unsigned short* __restrict__ T1,
                    unsigned short* __restrict__ T2, unsigned short* __restrict__ T3) {
    __shared__ float tile[64][68];
    const int z = blockIdx.z;
    const float* W = z == 0 ? W0 : z == 1 ? W1 : z == 2 ? W2 : W3;
    unsigned short* Wt = z == 0 ? T0 : z == 1 ? T1 : z == 2 ? T2 : T3;

    const int n0 = blockIdx.x * 64, k0 = blockIdx.y * 64;
    const int t = threadIdx.x;
    const int r = t >> 4, c4 = (t & 15) * 4;
#pragma unroll
    for (int i = 0; i < 4; ++i) {
        float4 v = *(const float4*)&W[(size_t)(k0 + r + i * 16) * Dmod + n0 + c4];
        tile[c4 + 0][r + i * 16] = v.x;
        tile[c4 + 1][r + i * 16] = v.y;
        tile[c4 + 2][r + i * 16] = v.z;
        tile[c4 + 3][r + i * 16] = v.w;
    }
    __syncthreads();
#pragma unroll
    for (int i = 0; i < 4; ++i) {
        ushort4 o;
        o.x = f2bf(tile[r + i * 16][c4 + 0]);
        o.y = f2bf(tile[r + i * 16][c4 + 1]);
        o.z = f2bf(tile[r + i * 16][c4 + 2]);
        o.w = f2bf(tile[r + i * 16][c4 + 3]);
        *(ushort4*)&Wt[(size_t)(n0 + r + i * 16) * Dmod + k0 + c4] = o;
    }
}

// ---------------------------------------------------------------------------
// MFMA GEMM core: 128x128 tile, BK=32, 4 waves (2x2), 64x64 per wave.
// ---------------------------------------------------------------------------
__device__ __forceinline__ void gemm_core(const unsigned short* __restrict__ A,
                                          const unsigned short* __restrict__ Wt,
                                          int m0, int n0, int K,
                                          short* As, short* Bs, f32x4 acc[4][4]) {
    const int t   = threadIdx.x;
    const int wid = t >> 6, l = t & 63;
    const int wr  = wid >> 1, wc = wid & 1;
    const int r16 = l & 15, g = l >> 4;
    const int srow = t >> 2;
    const int scol = (t & 3) * 8;

    for (int k0 = 0; k0 < K; k0 += 32) {
        __syncthreads();
#pragma unroll
        for (int c = 0; c < 2; ++c) {
            gload_lds16(A  + (size_t)(m0 + c * 64 + srow) * K + k0 + scol,
                        (char*)As + c * 4096 + wid * 1024);
            gload_lds16(Wt + (size_t)(n0 + c * 64 + srow) * K + k0 + scol,
                        (char*)Bs + c * 4096 + wid * 1024);
        }
        __syncthreads();
        bf16x8 af[4], bv[4];
#pragma unroll
        for (int mi = 0; mi < 4; ++mi)
            af[mi] = *(const bf16x8*)&As[(wr * 64 + mi * 16 + r16) * 32 + g * 8];
#pragma unroll
        for (int ni = 0; ni < 4; ++ni)
            bv[ni] = *(const bf16x8*)&Bs[(wc * 64 + ni * 16 + r16) * 32 + g * 8];
#pragma unroll
        for (int mi = 0; mi < 4; ++mi)
#pragma unroll
            for (int ni = 0; ni < 4; ++ni)
                acc[mi][ni] = __builtin_amdgcn_mfma_f32_16x16x32_bf16(
                    af[mi], bv[ni], acc[mi][ni], 0, 0, 0);
    }
}

// ---------------------------------------------------------------------------
// Fused QKV projection. Q gets QSCALE folded in (exp2-domain softmax).
// ---------------------------------------------------------------------------
__global__ __launch_bounds__(256)
void qkv_gemm(const unsigned short* __restrict__ xb,
              const unsigned short* __restrict__ wtq,
              const unsigned short* __restrict__ wtk,
              const unsigned short* __restrict__ wtv,
              unsigned short* __restrict__ Qb,
              unsigned short* __restrict__ Kb,
              unsigned short* __restrict__ Vtb) {
    __shared__ __align__(16) short As[128 * 32];
    __shared__ __align__(16) short Bs[128 * 32];
    const int region = blockIdx.x >> 3;
    const int n0 = (blockIdx.x & 7) * 128;
    const int m0 = blockIdx.y * 128;
    const unsigned short* Wt = region == 0 ? wtq : (region == 1 ? wtk : wtv);

    f32x4 acc[4][4];
    const f32x4 z = {0.f, 0.f, 0.f, 0.f};
#pragma unroll
    for (int i = 0; i < 4; ++i)
#pragma unroll
        for (int j = 0; j < 4; ++j) acc[i][j] = z;

    gemm_core(xb, Wt, m0, n0, Dmod, As, Bs, acc);

    const int t = threadIdx.x, wid = t >> 6, l = t & 63;
    const int wr = wid >> 1, wc = wid & 1, r16 = l & 15, g = l >> 4;

    if (region <= 1) {
        unsigned short* out = region ? Kb : Qb;
        const float qs = region == 0 ? QSCALE : 1.0f;
#pragma unroll
        for (int mi = 0; mi < 4; ++mi) {
            const int mrow = m0 + wr * 64 + mi * 16 + g * 4;
#pragma unroll
            for (int ni = 0; ni < 4; ++ni) {
                const int ncol = n0 + wc * 64 + ni * 16 + r16;
#pragma unroll
                for (int reg = 0; reg < 4; ++reg)
                    out[(size_t)(mrow + reg) * Dmod + ncol] = f2bf(acc[mi][ni][reg] * qs);
            }
        }
    } else {
#pragma unroll
        for (int mi = 0; mi < 4; ++mi) {
            const int mrow = m0 + wr * 64 + mi * 16 + g * 4;
            const int b = mrow >> 11, s = mrow & 2047;
#pragma unroll
            for (int ni = 0; ni < 4; ++ni) {
                const int n = n0 + wc * 64 + ni * 16 + r16;
                const int bh = b * NH + (n >> 6), d = n & 63;
                ushort4 o;
                o.x = f2bf(acc[mi][ni][0]); o.y = f2bf(acc[mi][ni][1]);
                o.z = f2bf(acc[mi][ni][2]); o.w = f2bf(acc[mi][ni][3]);
                *(ushort4*)&Vtb[((size_t)bh * DH + d) * SEQ + s] = o;
            }
        }
    }
}

// ---------------------------------------------------------------------------
// Output projection
// ---------------------------------------------------------------------------
__global__ __launch_bounds__(256)
void out_gemm(const unsigned short* __restrict__ Cx,
              const unsigned short* __restrict__ wto,
              const float* __restrict__ bias,
              float* __restrict__ out) {
    __shared__ __align__(16) short As[128 * 32];
    __shared__ __align__(16) short Bs[128 * 32];
    const int n0 = blockIdx.x * 128, m0 = blockIdx.y * 128;

    f32x4 acc[4][4];
    const f32x4 z = {0.f, 0.f, 0.f, 0.f};
#pragma unroll
    for (int i = 0; i < 4; ++i)
#pragma unroll
        for (int j = 0; j < 4; ++j) acc[i][j] = z;

    gemm_core(Cx, wto, m0, n0, Dmod, As, Bs, acc);

    const int t = threadIdx.x, wid = t >> 6, l = t & 63;
    const int wr = wid >> 1, wc = wid & 1, r16 = l & 15, g = l >> 4;
    float bv[4];
#pragma unroll
    for (int ni = 0; ni < 4; ++ni) bv[ni] = bias[n0 + wc * 64 + ni * 16 + r16];
#pragma unroll
    for (int mi = 0; mi < 4; ++mi) {
        const int mrow = m0 + wr * 64 + mi * 16 + g * 4;
#pragma unroll
        for (int ni = 0; ni < 4; ++ni) {
            const int ncol = n0 + wc * 64 + ni * 16 + r16;
#pragma unroll
            for (int reg = 0; reg < 4; ++reg)
                out[(size_t)(mrow + reg) * Dmod + ncol] = acc[mi][ni][reg] + bv[ni];
        }
    }
}

// ---------------------------------------------------------------------------
// MFMA flash attention, v3.1: 32x32x16 MFMA, in-register P, defer-max.
//  * launch_bounds(256,2): let the allocator breathe (v3.0's (256,4) forced
//    VGPR=64 -> scratch spills: +19MB writes, +17MB fetch, dur 109->125us).
//  * 512 blocks, pair-balanced (34 kv-tiles each), XCD-local bh decode.
//  * Swapped QK^T: S^T = mfma(K, Q), col = q = lane&31; row-reduce = 15 fmax
//    + 1 shfl_xor(32). P stays in registers: cvt_pk_bf16 + permlane32_swap.
//  * Defer-max (THR=8, exp2 domain): O-rescale is a rare wave-uniform branch.
//  * LDS = K/V double-buffer only (33 KB); Q fragments read from global.
// ---------------------------------------------------------------------------
__global__ __launch_bounds__(256, 2)
void attn_mfma(const unsigned short* __restrict__ Qg,
               const unsigned short* __restrict__ Kg,
               const unsigned short* __restrict__ Vtg,
               unsigned short* __restrict__ Ctx) {
    __shared__ __align__(16) short Ks[2][64 * 64];   // 16 KB
    __shared__ __align__(16) short Vs[2][64 * 64];   // 16 KB (Vt: [d][kv])
    __shared__ float sm[4][32];                      // per-wave scale/l bcast

    const int id   = blockIdx.x;                  // 0..511
    const int bh   = ((id >> 6) << 3) | (id & 7); // id%8 = XCD = bh low bits
    const int pidx = (id >> 3) & 7;
    const int b = bh >> 4, h = bh & 15;
    const int t = threadIdx.x, wid = t >> 6, l = t & 63;
    const int lo = l & 31, hi = l >> 5;
    const int srow8 = t >> 3, scolb = (t & 7) * 16;

    auto stageKV = [&](int jt, int buf) {
        const int k0s = jt * 64;
#pragma unroll
        for (int c = 0; c < 2; ++c) {
            const int row = c * 32 + srow8;
            const int swz = scolb ^ ((row & 7) << 4);
            gload_lds16((const char*)Kg + ((size_t)(b * SEQ + k0s + row) * Dmod + h * DH) * 2 + swz,
                        (char*)&Ks[buf][0] + c * 4096 + wid * 1024);
            gload_lds16((const char*)Vtg + ((size_t)(bh * DH + row) * SEQ + k0s) * 2 + swz,
                        (char*)&Vs[buf][0] + c * 4096 + wid * 1024);
        }
    };

    int cur = 0;
    for (int pass = 0; pass < 2; ++pass) {
        const int qt = pass ? pidx : 15 - pidx;   // heavy tile first
        const int q0 = qt * 128;
        const int qw0 = q0 + wid * 32;
        const int qg = qw0 + lo;                  // this lane's q row (S^T col)

        // Q fragments straight from global (B-operand: col=q=lane&31, k=d)
        bf16x8 bq[4];
#pragma unroll
        for (int dc = 0; dc < 4; ++dc)
            bq[dc] = *(const bf16x8*)&Qg[(size_t)(b * SEQ + qg) * Dmod + h * DH + dc * 16 + 8 * hi];

        stageKV(0, cur);

        float m_run = -1e30f, l_run = 0.f;
        f32x16 oacc[2];
#pragma unroll
        for (int nb = 0; nb < 2; ++nb)
#pragma unroll
            for (int r = 0; r < 16; ++r) oacc[nb][r] = 0.f;

        __syncthreads();                          // KV0 landed (+ buffers free)

        const int jmax = 2 * qt + 1;
        for (int jt = 0; jt <= jmax; ++jt) {
            if (jt < jmax) stageKV(jt + 1, cur ^ 1);   // prefetch next tile
            const char* Kc = (const char*)&Ks[cur][0];
            const char* Vc = (const char*)&Vs[cur][0];
            const bool diag = (jt >= 2 * qt);

#pragma unroll
            for (int c32 = 0; c32 < 2; ++c32) {
                // ---- S^T chunk = mfma(K, Q): rows kv (32), cols q (32)
                const int krow = c32 * 32 + lo;
                const int kswz = (krow & 7) << 4;
                bf16x8 ak[4];
#pragma unroll
                for (int dc = 0; dc < 4; ++dc)
                    ak[dc] = *(const bf16x8*)(Kc + krow * 128 + ((dc * 32 + 16 * hi) ^ kswz));
                f32x16 st;
#pragma unroll
                for (int r = 0; r < 16; ++r) st[r] = 0.f;
                __builtin_amdgcn_s_setprio(1);
#pragma unroll
                for (int dc = 0; dc < 4; ++dc)
                    st = __builtin_amdgcn_mfma_f32_32x32x16_bf16(ak[dc], bq[dc], st, 0, 0, 0);
                __builtin_amdgcn_s_setprio(0);

                if (diag) {
                    const int kvb = jt * 64 + c32 * 32 + 4 * hi;
#pragma unroll
                    for (int r = 0; r < 16; ++r) {
                        const int kvg = kvb + (r & 3) + 8 * (r >> 2);
                        if (kvg > qg) st[r] = -1e30f;
                    }
                }

                // ---- online softmax, defer-max (exp2 domain)
                float pmax = st[0];
#pragma unroll
                for (int r = 1; r < 16; ++r) pmax = fmaxf(pmax, st[r]);
                pmax = fmaxf(pmax, __shfl_xor(pmax, 32));

                if (!__all(pmax <= m_run + 8.f)) {       // rare rescale path
                    const float mnew = fmaxf(m_run, pmax);
                    const float sc = exp2f(m_run - mnew);
                    l_run *= sc;
                    m_run = mnew;
                    if (l < 32) sm[wid][lo] = sc;
                    asm volatile("s_waitcnt lgkmcnt(0)" ::: "memory");
#pragma unroll
                    for (int rq = 0; rq < 4; ++rq) {
                        const f32x4 s4 = *(const f32x4*)&sm[wid][8 * rq + 4 * hi];
#pragma unroll
                        for (int e = 0; e < 4; ++e) {
                            oacc[0][rq * 4 + e] *= s4[e];
                            oacc[1][rq * 4 + e] *= s4[e];
                        }
                    }
                }

                float p[16];
                float rsum = 0.f;
#pragma unroll
                for (int r = 0; r < 16; ++r) { p[r] = exp2f(st[r] - m_run); rsum += p[r]; }
                rsum += __shfl_xor(rsum, 32);
                l_run += rsum;

                // ---- in-register P -> A-fragments, PV accumulate
#pragma unroll
                for (int kb = 0; kb < 2; ++kb) {
                    unsigned int x, zz, y, w;
                    asm("v_cvt_pk_bf16_f32 %0, %1, %2" : "=v"(x)  : "v"(p[kb*8+0]), "v"(p[kb*8+1]));
                    asm("v_cvt_pk_bf16_f32 %0, %1, %2" : "=v"(zz) : "v"(p[kb*8+2]), "v"(p[kb*8+3]));
                    asm("v_cvt_pk_bf16_f32 %0, %1, %2" : "=v"(y)  : "v"(p[kb*8+4]), "v"(p[kb*8+5]));
                    asm("v_cvt_pk_bf16_f32 %0, %1, %2" : "=v"(w)  : "v"(p[kb*8+6]), "v"(p[kb*8+7]));
                    asm volatile("v_permlane32_swap_b32 %0, %1" : "+v"(x),  "+v"(y));
                    asm volatile("v_permlane32_swap_b32 %0, %1" : "+v"(zz), "+v"(w));
                    u32x4 aw; aw[0] = x; aw[1] = zz; aw[2] = y; aw[3] = w;
                    const bf16x8 paf = __builtin_bit_cast(bf16x8, aw);

                    const int vbyte = c32 * 64 + kb * 32 + 16 * hi;
                    const int row0 = lo, row1 = 32 + lo;
                    const bf16x8 vb0 = *(const bf16x8*)(Vc + row0 * 128 + (vbyte ^ ((row0 & 7) << 4)));
                    const bf16x8 vb1 = *(const bf16x8*)(Vc + row1 * 128 + (vbyte ^ ((row1 & 7) << 4)));

                    __builtin_amdgcn_s_setprio(1);
                    oacc[0] = __builtin_amdgcn_mfma_f32_32x32x16_bf16(paf, vb0, oacc[0], 0, 0, 0);
                    oacc[1] = __builtin_amdgcn_mfma_f32_32x32x16_bf16(paf, vb1, oacc[1], 0, 0, 0);
                    __builtin_amdgcn_s_setprio(0);
                }
            }
            __syncthreads();    // prefetch landed (vmcnt drain); reads done
            cur ^= 1;
        }

        // ---- epilogue: broadcast l to O-row domain, write ctx bf16
        if (l < 32) sm[wid][lo] = l_run;
        asm volatile("s_waitcnt lgkmcnt(0)" ::: "memory");
#pragma unroll
        for (int rq = 0; rq < 4; ++rq) {
            const f32x4 lv = *(const f32x4*)&sm[wid][8 * rq + 4 * hi];
#pragma unroll
            for (int e = 0; e < 4; ++e) {
                const float inv = 1.0f / lv[e];
                const int qrow = qw0 + 8 * rq + 4 * hi + e;
                const size_t rb = (size_t)(b * SEQ + qrow) * Dmod + h * DH + lo;
                Ctx[rb]      = f2bf(oacc[0][rq * 4 + e] * inv);
                Ctx[rb + 32] = f2bf(oacc[1][rq * 4 + e] * inv);
            }
        }
    }
}

// ---------------------------------------------------------------------------
extern "C" void kernel_launch(void* const* d_in, const int* in_sizes, int n_in,
                              void* d_out, int out_size, void* d_ws, size_t ws_size,
                              hipStream_t stream) {
    const float* x  = (const float*)d_in[0];
    const float* Wq = (const float*)d_in[1];
    const float* Wk = (const float*)d_in[2];
    const float* Wv = (const float*)d_in[3];
    const float* Wo = (const float*)d_in[4];
    const float* bo = (const float*)d_in[5];
    float* out = (float*)d_out;

    const size_t MD = (size_t)Mtot * Dmod;
    const size_t DD = (size_t)Dmod * Dmod;
    unsigned short* xb  = (unsigned short*)d_ws;
    unsigned short* wtq = xb  + MD;
    unsigned short* wtk = wtq + DD;
    unsigned short* wtv = wtk + DD;
    unsigned short* wto = wtv + DD;
    unsigned short* Qb  = wto + DD;
    unsigned short* Kb  = Qb  + MD;
    unsigned short* Vtb = Kb  + MD;
    unsigned short* Cx  = Vtb + MD;

    cvt_bf16<<<2048, 256, 0, stream>>>(x, xb, (int)(MD / 4));
    transpose_cvt4<<<dim3(16, 16, 4), 256, 0, stream>>>(Wq, Wk, Wv, Wo,
                                                        wtq, wtk, wtv, wto);

    qkv_gemm<<<dim3(24, 64), 256, 0, stream>>>(xb, wtq, wtk, wtv, Qb, Kb, Vtb);

    attn_mfma<<<512, 256, 0, stream>>>(Qb, Kb, Vtb, Cx);

    out_gemm<<<dim3(8, 64), 256, 0, stream>>>(Cx, wto, bo, out);
}

// Round 6
// 190.587 us; speedup vs baseline: 1.2514x; 1.0707x over previous
//
#include <hip/hip_runtime.h>
#include <hip/hip_bf16.h>
#include <math.h>

typedef __attribute__((ext_vector_type(8))) short bf16x8;   // 8 bf16 = 4 VGPR
typedef __attribute__((ext_vector_type(4))) float f32x4;
typedef __attribute__((ext_vector_type(16))) float f32x16;
typedef __attribute__((ext_vector_type(4))) unsigned int u32x4;

static constexpr int Mtot = 8192;   // B*S
static constexpr int Dmod = 1024;
static constexpr int SEQ  = 2048;
static constexpr int NH   = 16;
static constexpr int DH   = 64;

// softmax scale folded into Q projection, in exp2 domain: (1/8) * log2(e)
static constexpr float QSCALE = 0.18033688011112042f;

// fp32 -> bf16 RNE
__device__ __forceinline__ unsigned short f2bf(float x) {
    unsigned int u = __float_as_uint(x);
    u += 0x7fff + ((u >> 16) & 1);
    return (unsigned short)(u >> 16);
}

// async global->LDS, 16B per lane. LDS dest = wave-uniform base + lane*16.
__device__ __forceinline__ void gload_lds16(const void* g, void* l) {
    __builtin_amdgcn_global_load_lds(
        (const __attribute__((address_space(1))) unsigned int*)g,
        (__attribute__((address_space(3))) unsigned int*)l, 16, 0, 0);
}

// ---------------------------------------------------------------------------
// x fp32 -> bf16
// ---------------------------------------------------------------------------
__global__ __launch_bounds__(256)
void cvt_bf16(const float* __restrict__ in, unsigned short* __restrict__ out, int n4) {
    int i = blockIdx.x * blockDim.x + threadIdx.x;
    const int stride = gridDim.x * blockDim.x;
    for (; i < n4; i += stride) {
        float4 v = ((const float4*)in)[i];
        ushort4 o;
        o.x = f2bf(v.x); o.y = f2bf(v.y); o.z = f2bf(v.z); o.w = f2bf(v.w);
        ((ushort4*)out)[i] = o;
    }
}

// ---------------------------------------------------------------------------
// All four W[k][n] fp32 -> Wt[n][k] bf16 in one launch (z = which weight)
// ---------------------------------------------------------------------------
__global__ __launch_bounds__(256)
void transpose_cvt4(const float* __restrict__ W0, const float* __restrict__ W1,
                    const float* __restrict__ W2, const float* __restrict__ W3,
                    unsigned short* __restrict__ T0, unsigned short* __restrict__ T1,
                    unsigned short* __restrict__ T2, unsigned short* __restrict__ T3) {
    __shared__ float tile[64][68];
    const int z = blockIdx.z;
    const float* W = z == 0 ? W0 : z == 1 ? W1 : z == 2 ? W2 : W3;
    unsigned short* Wt = z == 0 ? T0 : z == 1 ? T1 : z == 2 ? T2 : T3;

    const int n0 = blockIdx.x * 64, k0 = blockIdx.y * 64;
    const int t = threadIdx.x;
    const int r = t >> 4, c4 = (t & 15) * 4;
#pragma unroll
    for (int i = 0; i < 4; ++i) {
        float4 v = *(const float4*)&W[(size_t)(k0 + r + i * 16) * Dmod + n0 + c4];
        tile[c4 + 0][r + i * 16] = v.x;
        tile[c4 + 1][r + i * 16] = v.y;
        tile[c4 + 2][r + i * 16] = v.z;
        tile[c4 + 3][r + i * 16] = v.w;
    }
    __syncthreads();
#pragma unroll
    for (int i = 0; i < 4; ++i) {
        ushort4 o;
        o.x = f2bf(tile[r + i * 16][c4 + 0]);
        o.y = f2bf(tile[r + i * 16][c4 + 1]);
        o.z = f2bf(tile[r + i * 16][c4 + 2]);
        o.w = f2bf(tile[r + i * 16][c4 + 3]);
        *(ushort4*)&Wt[(size_t)(n0 + r + i * 16) * Dmod + k0 + c4] = o;
    }
}

// ---------------------------------------------------------------------------
// 256x256 8-phase GEMM (T3+T4 template). BK=64, 8 waves (2M x 4N), 512 thr,
// 128 KB LDS dbuf. Per K-tile: 4 phases, each {stage 1 half | vmcnt(6) gate
// at kh boundaries | raw barrier | ds_read | lgkmcnt+sched_barrier | 16 MFMA
// in setprio(1)}. LDS regions per buffer: [A-k0|B-k0|A-k1|B-k1] x 16 KB.
// Swizzle: byte ^= ((row>>1)&3)<<4 on [256][32]-bf16 (64B rows); staged via
// pre-swizzled global source (involution), LDS dest linear.
// MODE 0: qkv (A=xb, B=wtq..wtv concat, N=3072). MODE 1: out proj (+bias).
// ---------------------------------------------------------------------------
template<int MODE>
__global__ __launch_bounds__(512)
void gemm256(const unsigned short* __restrict__ A,
             const unsigned short* __restrict__ Bw,
             const float* __restrict__ bias,
             unsigned short* __restrict__ Qb,
             unsigned short* __restrict__ Kb,
             unsigned short* __restrict__ Vtb,
             float* __restrict__ Fout) {
    __shared__ __align__(16) char lds[131072];

    const int id  = blockIdx.x;
    const int xcd = id & 7, idx = id >> 3;
    constexpr int NTN = MODE == 0 ? 12 : 4;
    const int mt = xcd * 4 + idx / NTN;
    const int nt = idx % NTN;
    const int m0 = mt * 256, n0 = nt * 256;

    const int t = threadIdx.x;
    const int wid = t >> 6, l = t & 63;
    const int wm = wid >> 2, wn = wid & 3;
    const int r16 = l & 15, g = l >> 4;

    // stage one 16KB half-tile ([256 rows][32 k] bf16), pre-swizzled source
    auto stage = [&](const unsigned short* src, int row0, int kt, int kh, int regionOff) {
        char* dst = lds + regionOff + wid * 1024;
#pragma unroll
        for (int r = 0; r < 2; ++r) {
            const int o  = r * 8192 + t * 16;
            const int lg = o ^ (((o >> 7) & 3) << 4);
            gload_lds16((const char*)src + (size_t)(row0 + (lg >> 6)) * 2048
                            + kt * 128 + kh * 64 + (lg & 63),
                        dst + r * 8192);
        }
    };

    f32x4 acc[8][4];
    const f32x4 z = {0.f, 0.f, 0.f, 0.f};
#pragma unroll
    for (int i = 0; i < 8; ++i)
#pragma unroll
        for (int j = 0; j < 4; ++j) acc[i][j] = z;

    // prologue: K-tile 0 -> buf0 (issue order fixes vmcnt bookkeeping)
    stage(A,  m0, 0, 0, 0);
    stage(Bw, n0, 0, 0, 16384);
    stage(A,  m0, 0, 1, 32768);
    stage(Bw, n0, 0, 1, 49152);

    const int arow0 = wm * 128 + r16;
    const int brow0 = wn * 64 + r16;
    const int gb = g * 16;

    for (int kt = 0; kt < 16; ++kt) {
        const int buf  = (kt & 1) << 16;
        const int nbuf = buf ^ 65536;
        const int ktn  = kt < 15 ? kt + 1 : 15;   // clamp keeps vmcnt uniform
        bf16x8 af[8], bv[2];

        // ===== phase 0: kh0, n-frags 0..1 =====
        stage(A, m0, ktn, 0, nbuf);
        asm volatile("s_waitcnt vmcnt(6)" ::: "memory");  // A-k0,B-k0 of kt landed
        __builtin_amdgcn_s_barrier();
#pragma unroll
        for (int mi = 0; mi < 8; ++mi) {
            const int row = arow0 + mi * 16;
            af[mi] = *(const bf16x8*)(lds + buf
                      + ((row * 64 + gb) ^ (((row >> 1) & 3) << 4)));
        }
#pragma unroll
        for (int ni = 0; ni < 2; ++ni) {
            const int row = brow0 + ni * 16;
            bv[ni] = *(const bf16x8*)(lds + buf + 16384
                      + ((row * 64 + gb) ^ (((row >> 1) & 3) << 4)));
        }
        asm volatile("s_waitcnt lgkmcnt(0)" ::: "memory");
        __builtin_amdgcn_sched_barrier(0);
        __builtin_amdgcn_s_setprio(1);
#pragma unroll
        for (int mi = 0; mi < 8; ++mi)
#pragma unroll
            for (int ni = 0; ni < 2; ++ni)
                acc[mi][ni] = __builtin_amdgcn_mfma_f32_16x16x32_bf16(
                    af[mi], bv[ni], acc[mi][ni], 0, 0, 0);
        __builtin_amdgcn_s_setprio(0);

        // ===== phase 1: kh0, n-frags 2..3 (reuse af) =====
        stage(Bw, n0, ktn, 0, nbuf + 16384);
#pragma unroll
        for (int ni = 0; ni < 2; ++ni) {
            const int row = brow0 + (2 + ni) * 16;
            bv[ni] = *(const bf16x8*)(lds + buf + 16384
                      + ((row * 64 + gb) ^ (((row >> 1) & 3) << 4)));
        }
        asm volatile("s_waitcnt lgkmcnt(0)" ::: "memory");
        __builtin_amdgcn_sched_barrier(0);
        __builtin_amdgcn_s_setprio(1);
#pragma unroll
        for (int mi = 0; mi < 8; ++mi)
#pragma unroll
            for (int ni = 0; ni < 2; ++ni)
                acc[mi][2 + ni] = __builtin_amdgcn_mfma_f32_16x16x32_bf16(
                    af[mi], bv[ni], acc[mi][2 + ni], 0, 0, 0);
        __builtin_amdgcn_s_setprio(0);

        // ===== phase 2: kh1, n-frags 0..1 =====
        stage(A, m0, ktn, 1, nbuf + 32768);
        asm volatile("s_waitcnt vmcnt(6)" ::: "memory");  // A-k1,B-k1 of kt landed
        __builtin_amdgcn_s_barrier();
#pragma unroll
        for (int mi = 0; mi < 8; ++mi) {
            const int row = arow0 + mi * 16;
            af[mi] = *(const bf16x8*)(lds + buf + 32768
                      + ((row * 64 + gb) ^ (((row >> 1) & 3) << 4)));
        }
#pragma unroll
        for (int ni = 0; ni < 2; ++ni) {
            const int row = brow0 + ni * 16;
            bv[ni] = *(const bf16x8*)(lds + buf + 49152
                      + ((row * 64 + gb) ^ (((row >> 1) & 3) << 4)));
        }
        asm volatile("s_waitcnt lgkmcnt(0)" ::: "memory");
        __builtin_amdgcn_sched_barrier(0);
        __builtin_amdgcn_s_setprio(1);
#pragma unroll
        for (int mi = 0; mi < 8; ++mi)
#pragma unroll
            for (int ni = 0; ni < 2; ++ni)
                acc[mi][ni] = __builtin_amdgcn_mfma_f32_16x16x32_bf16(
                    af[mi], bv[ni], acc[mi][ni], 0, 0, 0);
        __builtin_amdgcn_s_setprio(0);

        // ===== phase 3: kh1, n-frags 2..3 (reuse af) =====
        stage(Bw, n0, ktn, 1, nbuf + 49152);
#pragma unroll
        for (int ni = 0; ni < 2; ++ni) {
            const int row = brow0 + (2 + ni) * 16;
            bv[ni] = *(const bf16x8*)(lds + buf + 49152
                      + ((row * 64 + gb) ^ (((row >> 1) & 3) << 4)));
        }
        asm volatile("s_waitcnt lgkmcnt(0)" ::: "memory");
        __builtin_amdgcn_sched_barrier(0);
        __builtin_amdgcn_s_setprio(1);
#pragma unroll
        for (int mi = 0; mi < 8; ++mi)
#pragma unroll
            for (int ni = 0; ni < 2; ++ni)
                acc[mi][2 + ni] = __builtin_amdgcn_mfma_f32_16x16x32_bf16(
                    af[mi], bv[ni], acc[mi][2 + ni], 0, 0, 0);
        __builtin_amdgcn_s_setprio(0);
    }

    // ===== epilogue =====
    if constexpr (MODE == 0) {
        const int region = n0 >> 10;             // 0=Q, 1=K, 2=V
        if (region <= 1) {
            unsigned short* outp = region ? Kb : Qb;
            const float qs = region == 0 ? QSCALE : 1.0f;
#pragma unroll
            for (int mi = 0; mi < 8; ++mi) {
                const int mrow = m0 + wm * 128 + mi * 16 + g * 4;
#pragma unroll
                for (int ni = 0; ni < 4; ++ni) {
                    const int ncol = (n0 & 1023) + wn * 64 + ni * 16 + r16;
#pragma unroll
                    for (int reg = 0; reg < 4; ++reg)
                        outp[(size_t)(mrow + reg) * Dmod + ncol] = f2bf(acc[mi][ni][reg] * qs);
                }
            }
        } else {
#pragma unroll
            for (int mi = 0; mi < 8; ++mi) {
                const int mrow = m0 + wm * 128 + mi * 16 + g * 4;
                const int bidx = mrow >> 11, s = mrow & 2047;
#pragma unroll
                for (int ni = 0; ni < 4; ++ni) {
                    const int n = (n0 & 1023) + wn * 64 + ni * 16 + r16;
                    const int bh = bidx * NH + (n >> 6), d = n & 63;
                    ushort4 o;
                    o.x = f2bf(acc[mi][ni][0]); o.y = f2bf(acc[mi][ni][1]);
                    o.z = f2bf(acc[mi][ni][2]); o.w = f2bf(acc[mi][ni][3]);
                    *(ushort4*)&Vtb[((size_t)bh * DH + d) * SEQ + s] = o;
                }
            }
        }
    } else {
        float bb[4];
#pragma unroll
        for (int ni = 0; ni < 4; ++ni)
            bb[ni] = bias[n0 + wn * 64 + ni * 16 + r16];
#pragma unroll
        for (int mi = 0; mi < 8; ++mi) {
            const int mrow = m0 + wm * 128 + mi * 16 + g * 4;
#pragma unroll
            for (int ni = 0; ni < 4; ++ni) {
                const int ncol = n0 + wn * 64 + ni * 16 + r16;
#pragma unroll
                for (int reg = 0; reg < 4; ++reg)
                    Fout[(size_t)(mrow + reg) * Dmod + ncol] = acc[mi][ni][reg] + bb[ni];
            }
        }
    }
}

// ---------------------------------------------------------------------------
// MFMA flash attention, v3.1 (unchanged from round 5; 94.6 us).
// ---------------------------------------------------------------------------
__global__ __launch_bounds__(256, 2)
void attn_mfma(const unsigned short* __restrict__ Qg,
               const unsigned short* __restrict__ Kg,
               const unsigned short* __restrict__ Vtg,
               unsigned short* __restrict__ Ctx) {
    __shared__ __align__(16) short Ks[2][64 * 64];   // 16 KB
    __shared__ __align__(16) short Vs[2][64 * 64];   // 16 KB (Vt: [d][kv])
    __shared__ float sm[4][32];                      // per-wave scale/l bcast

    const int id   = blockIdx.x;                  // 0..511
    const int bh   = ((id >> 6) << 3) | (id & 7); // id%8 = XCD = bh low bits
    const int pidx = (id >> 3) & 7;
    const int b = bh >> 4, h = bh & 15;
    const int t = threadIdx.x, wid = t >> 6, l = t & 63;
    const int lo = l & 31, hi = l >> 5;
    const int srow8 = t >> 3, scolb = (t & 7) * 16;

    auto stageKV = [&](int jt, int buf) {
        const int k0s = jt * 64;
#pragma unroll
        for (int c = 0; c < 2; ++c) {
            const int row = c * 32 + srow8;
            const int swz = scolb ^ ((row & 7) << 4);
            gload_lds16((const char*)Kg + ((size_t)(b * SEQ + k0s + row) * Dmod + h * DH) * 2 + swz,
                        (char*)&Ks[buf][0] + c * 4096 + wid * 1024);
            gload_lds16((const char*)Vtg + ((size_t)(bh * DH + row) * SEQ + k0s) * 2 + swz,
                        (char*)&Vs[buf][0] + c * 4096 + wid * 1024);
        }
    };

    int cur = 0;
    for (int pass = 0; pass < 2; ++pass) {
        const int qt = pass ? pidx : 15 - pidx;   // heavy tile first
        const int q0 = qt * 128;
        const int qw0 = q0 + wid * 32;
        const int qg = qw0 + lo;                  // this lane's q row (S^T col)

        // Q fragments straight from global (B-operand: col=q=lane&31, k=d)
        bf16x8 bq[4];
#pragma unroll
        for (int dc = 0; dc < 4; ++dc)
            bq[dc] = *(const bf16x8*)&Qg[(size_t)(b * SEQ + qg) * Dmod + h * DH + dc * 16 + 8 * hi];

        stageKV(0, cur);

        float m_run = -1e30f, l_run = 0.f;
        f32x16 oacc[2];
#pragma unroll
        for (int nb = 0; nb < 2; ++nb)
#pragma unroll
            for (int r = 0; r < 16; ++r) oacc[nb][r] = 0.f;

        __syncthreads();                          // KV0 landed (+ buffers free)

        const int jmax = 2 * qt + 1;
        for (int jt = 0; jt <= jmax; ++jt) {
            if (jt < jmax) stageKV(jt + 1, cur ^ 1);   // prefetch next tile
            const char* Kc = (const char*)&Ks[cur][0];
            const char* Vc = (const char*)&Vs[cur][0];
            const bool diag = (jt >= 2 * qt);

#pragma unroll
            for (int c32 = 0; c32 < 2; ++c32) {
                // ---- S^T chunk = mfma(K, Q): rows kv (32), cols q (32)
                const int krow = c32 * 32 + lo;
                const int kswz = (krow & 7) << 4;
                bf16x8 ak[4];
#pragma unroll
                for (int dc = 0; dc < 4; ++dc)
                    ak[dc] = *(const bf16x8*)(Kc + krow * 128 + ((dc * 32 + 16 * hi) ^ kswz));
                f32x16 st;
#pragma unroll
                for (int r = 0; r < 16; ++r) st[r] = 0.f;
                __builtin_amdgcn_s_setprio(1);
#pragma unroll
                for (int dc = 0; dc < 4; ++dc)
                    st = __builtin_amdgcn_mfma_f32_32x32x16_bf16(ak[dc], bq[dc], st, 0, 0, 0);
                __builtin_amdgcn_s_setprio(0);

                if (diag) {
                    const int kvb = jt * 64 + c32 * 32 + 4 * hi;
#pragma unroll
                    for (int r = 0; r < 16; ++r) {
                        const int kvg = kvb + (r & 3) + 8 * (r >> 2);
                        if (kvg > qg) st[r] = -1e30f;
                    }
                }

                // ---- online softmax, defer-max (exp2 domain)
                float pmax = st[0];
#pragma unroll
                for (int r = 1; r < 16; ++r) pmax = fmaxf(pmax, st[r]);
                pmax = fmaxf(pmax, __shfl_xor(pmax, 32));

                if (!__all(pmax <= m_run + 8.f)) {       // rare rescale path
                    const float mnew = fmaxf(m_run, pmax);
                    const float sc = exp2f(m_run - mnew);
                    l_run *= sc;
                    m_run = mnew;
                    if (l < 32) sm[wid][lo] = sc;
                    asm volatile("s_waitcnt lgkmcnt(0)" ::: "memory");
#pragma unroll
                    for (int rq = 0; rq < 4; ++rq) {
                        const f32x4 s4 = *(const f32x4*)&sm[wid][8 * rq + 4 * hi];
#pragma unroll
                        for (int e = 0; e < 4; ++e) {
                            oacc[0][rq * 4 + e] *= s4[e];
                            oacc[1][rq * 4 + e] *= s4[e];
                        }
                    }
                }

                float p[16];
                float rsum = 0.f;
#pragma unroll
                for (int r = 0; r < 16; ++r) { p[r] = exp2f(st[r] - m_run); rsum += p[r]; }
                rsum += __shfl_xor(rsum, 32);
                l_run += rsum;

                // ---- in-register P -> A-fragments, PV accumulate
#pragma unroll
                for (int kb = 0; kb < 2; ++kb) {
                    unsigned int x, zz, y, w;
                    asm("v_cvt_pk_bf16_f32 %0, %1, %2" : "=v"(x)  : "v"(p[kb*8+0]), "v"(p[kb*8+1]));
                    asm("v_cvt_pk_bf16_f32 %0, %1, %2" : "=v"(zz) : "v"(p[kb*8+2]), "v"(p[kb*8+3]));
                    asm("v_cvt_pk_bf16_f32 %0, %1, %2" : "=v"(y)  : "v"(p[kb*8+4]), "v"(p[kb*8+5]));
                    asm("v_cvt_pk_bf16_f32 %0, %1, %2" : "=v"(w)  : "v"(p[kb*8+6]), "v"(p[kb*8+7]));
                    asm volatile("v_permlane32_swap_b32 %0, %1" : "+v"(x),  "+v"(y));
                    asm volatile("v_permlane32_swap_b32 %0, %1" : "+v"(zz), "+v"(w));
                    u32x4 aw; aw[0] = x; aw[1] = zz; aw[2] = y; aw[3] = w;
                    const bf16x8 paf = __builtin_bit_cast(bf16x8, aw);

                    const int vbyte = c32 * 64 + kb * 32 + 16 * hi;
                    const int row0 = lo, row1 = 32 + lo;
                    const bf16x8 vb0 = *(const bf16x8*)(Vc + row0 * 128 + (vbyte ^ ((row0 & 7) << 4)));
                    const bf16x8 vb1 = *(const bf16x8*)(Vc + row1 * 128 + (vbyte ^ ((row1 & 7) << 4)));

                    __builtin_amdgcn_s_setprio(1);
                    oacc[0] = __builtin_amdgcn_mfma_f32_32x32x16_bf16(paf, vb0, oacc[0], 0, 0, 0);
                    oacc[1] = __builtin_amdgcn_mfma_f32_32x32x16_bf16(paf, vb1, oacc[1], 0, 0, 0);
                    __builtin_amdgcn_s_setprio(0);
                }
            }
            __syncthreads();    // prefetch landed (vmcnt drain); reads done
            cur ^= 1;
        }

        // ---- epilogue: broadcast l to O-row domain, write ctx bf16
        if (l < 32) sm[wid][lo] = l_run;
        asm volatile("s_waitcnt lgkmcnt(0)" ::: "memory");
#pragma unroll
        for (int rq = 0; rq < 4; ++rq) {
            const f32x4 lv = *(const f32x4*)&sm[wid][8 * rq + 4 * hi];
#pragma unroll
            for (int e = 0; e < 4; ++e) {
                const float inv = 1.0f / lv[e];
                const int qrow = qw0 + 8 * rq + 4 * hi + e;
                const size_t rb = (size_t)(b * SEQ + qrow) * Dmod + h * DH + lo;
                Ctx[rb]      = f2bf(oacc[0][rq * 4 + e] * inv);
                Ctx[rb + 32] = f2bf(oacc[1][rq * 4 + e] * inv);
            }
        }
    }
}

// ---------------------------------------------------------------------------
extern "C" void kernel_launch(void* const* d_in, const int* in_sizes, int n_in,
                              void* d_out, int out_size, void* d_ws, size_t ws_size,
                              hipStream_t stream) {
    const float* x  = (const float*)d_in[0];
    const float* Wq = (const float*)d_in[1];
    const float* Wk = (const float*)d_in[2];
    const float* Wv = (const float*)d_in[3];
    const float* Wo = (const float*)d_in[4];
    const float* bo = (const float*)d_in[5];
    float* out = (float*)d_out;

    const size_t MD = (size_t)Mtot * Dmod;
    const size_t DD = (size_t)Dmod * Dmod;
    unsigned short* xb  = (unsigned short*)d_ws;
    unsigned short* wtq = xb  + MD;
    unsigned short* wtk = wtq + DD;
    unsigned short* wtv = wtk + DD;
    unsigned short* wto = wtv + DD;
    unsigned short* Qb  = wto + DD;
    unsigned short* Kb  = Qb  + MD;
    unsigned short* Vtb = Kb  + MD;
    unsigned short* Cx  = Vtb + MD;

    cvt_bf16<<<2048, 256, 0, stream>>>(x, xb, (int)(MD / 4));
    transpose_cvt4<<<dim3(16, 16, 4), 256, 0, stream>>>(Wq, Wk, Wv, Wo,
                                                        wtq, wtk, wtv, wto);

    // qkv as one 8192 x 3072 GEMM (wtq/wtk/wtv contiguous in ws)
    gemm256<0><<<384, 512, 0, stream>>>(xb, wtq, nullptr, Qb, Kb, Vtb, nullptr);

    attn_mfma<<<512, 256, 0, stream>>>(Qb, Kb, Vtb, Cx);

    gemm256<1><<<128, 512, 0, stream>>>(Cx, wto, bo, nullptr, nullptr, nullptr, out);
}